// Round 2
// baseline (163.762 us; speedup 1.0000x reference)
//
#include <hip/hip_runtime.h>

#define M_NODES 20000
#define N_EDGES_C 320000
#define DIM 512

typedef __attribute__((ext_vector_type(4))) float f32x4;
typedef __attribute__((ext_vector_type(2))) __bf16 bf16x2;
typedef __attribute__((ext_vector_type(4))) __bf16 bf16x4;
typedef __attribute__((ext_vector_type(8))) __bf16 bf16x8;

// ---------------- async global->LDS (16B per lane) ----------------
__device__ __forceinline__ void async16(__bf16* lds, const __bf16* g) {
  __builtin_amdgcn_global_load_lds(
      (const __attribute__((address_space(1))) void*)g,
      (__attribute__((address_space(3))) void*)lds, 16, 0, 0);
}

// ---------------- 1. convert: hb = bf16(norm[row] * h) ----------------
__global__ __launch_bounds__(256) void convert_k(const float* __restrict__ h,
                                                 const float* __restrict__ norm,
                                                 __bf16* __restrict__ hb) {
  int i = blockIdx.x * 256 + threadIdx.x;   // one float4 group each; 2,560,000 total
  int elem = i * 4;
  int row = elem >> 9;
  float s = norm[row];
  f32x4 v = *(const f32x4*)&h[elem];
  bf16x4 o;
  o.x = (__bf16)(v.x * s);
  o.y = (__bf16)(v.y * s);
  o.z = (__bf16)(v.z * s);
  o.w = (__bf16)(v.w * s);
  *(bf16x4*)&hb[elem] = o;
}

// ---------------- 2. weight transpose -> bf16 W^T [n][k] ----------------
__global__ void transpose_w(const float* __restrict__ w, __bf16* __restrict__ wT) {
  __shared__ float tile[32][33];
  int bx = blockIdx.x * 32, by = blockIdx.y * 32;
  int tx = threadIdx.x, ty = threadIdx.y;
  tile[ty][tx] = w[(by + ty) * DIM + bx + tx];   // coalesced read of weight[k][n]
  __syncthreads();
  wT[(bx + ty) * DIM + by + tx] = (__bf16)tile[tx][ty];  // coalesced write of wT[n][k]
}

// ---------------- 3. CSR build ----------------
__global__ __launch_bounds__(256) void count_k(const int* __restrict__ dst,
                                               int* __restrict__ counts) {
  int e = blockIdx.x * 256 + threadIdx.x;
  if (e < N_EDGES_C) atomicAdd(&counts[dst[e]], 1);
}

// single-block scan: 1000 threads x 20 consecutive elements, ~3 global round-trips
__global__ __launch_bounds__(1024) void scan_k(int* __restrict__ counts,
                                               int* __restrict__ offsets) {
  const int tid = threadIdx.x;
  const int lane = tid & 63, wid = tid >> 6;
  __shared__ int wsum[16], wpre[16];
  int v[20];
  int s = 0;
  const int base = tid * 20;
  if (tid < 1000) {
#pragma unroll
    for (int i = 0; i < 20; ++i) { v[i] = counts[base + i]; s += v[i]; }
  }
  int x = s;
#pragma unroll
  for (int off = 1; off < 64; off <<= 1) {
    int t = __shfl_up(x, off, 64);
    if (lane >= off) x += t;
  }
  if (lane == 63) wsum[wid] = x;
  __syncthreads();
  if (wid == 0 && lane < 16) {
    int wv = wsum[lane];
#pragma unroll
    for (int off = 1; off < 16; off <<= 1) {
      int t = __shfl_up(wv, off, 64);
      if (lane >= off) wv += t;
    }
    wpre[lane] = wv;
  }
  __syncthreads();
  const int wbase = wid ? wpre[wid - 1] : 0;
  const int excl = wbase + x - s;    // exclusive prefix over thread sums
  if (tid < 1000) {
    int run = excl;
#pragma unroll
    for (int i = 0; i < 20; ++i) {
      offsets[base + i] = run;
      counts[base + i] = run;        // counts reused as fill cursor
      run += v[i];
    }
  }
  if (tid == 0) offsets[M_NODES] = wpre[15];
}

__global__ __launch_bounds__(256) void fill_k(const int* __restrict__ src,
                                              const int* __restrict__ dst,
                                              int* __restrict__ cursor,
                                              int* __restrict__ esrc) {
  int e = blockIdx.x * 256 + threadIdx.x;
  if (e < N_EDGES_C) {
    int p = atomicAdd(&cursor[dst[e]], 1);
    esrc[p] = src[e];
  }
}

// ---------------- 4. aggregate, XCD-pinned D-panels ----------------
// panel = blockIdx.x % 8  -> round-robin dispatch pins panel p to XCD p.
// Panel working set = 20000 x 64 cols x 2B = 2.56 MB -> fits 4 MB per-XCD L2.
// One wave per node: half-waves (lanes 0-31 / 32-63) take even/odd edges,
// each lane accumulates one bf16x2 column pair; __shfl_xor(32) combines.
__global__ __launch_bounds__(256) void aggregate_k(const __bf16* __restrict__ hb,
                                                   const int* __restrict__ offs,
                                                   const int* __restrict__ esrc,
                                                   __bf16* __restrict__ aggb) {
  const int panel = blockIdx.x & 7;           // -> XCD id (round-robin dispatch)
  const int group = blockIdx.x >> 3;
  const int wv = threadIdx.x >> 6;
  const int node = group * 4 + wv;
  const int lane = threadIdx.x & 63;
  const int half = lane >> 5;                 // 0: even edges, 1: odd edges
  const int col = (lane & 31) * 2;            // column pair within 64-col panel

  const int beg = offs[node], end = offs[node + 1];
  const size_t pbase = (size_t)panel * 64 + col;

  float a0 = 0.f, a1 = 0.f;
  int j = beg + half;
  int nexts = (j < end) ? esrc[j] : 0;
  while (j < end) {
    int s = nexts;
    int jn = j + 2;
    if (jn < end) nexts = esrc[jn];           // prefetch next index
    bf16x2 v = *(const bf16x2*)&hb[(size_t)s * DIM + pbase];
    a0 += (float)v.x;
    a1 += (float)v.y;
    j = jn;
  }
  // combine even/odd halves (lane i <-> lane i^32 hold same column pair)
  a0 += __shfl_xor(a0, 32, 64);
  a1 += __shfl_xor(a1, 32, 64);
  if (half == 0) {
    bf16x2 o;
    o.x = (__bf16)a0;
    o.y = (__bf16)a1;
    *(bf16x2*)&aggb[(size_t)node * DIM + pbase] = o;
  }
}

// ---------------- 5. GEMM: out = relu(norm * (aggb @ W) + bias) ----------------
// A = aggb [M][512] bf16 row-major; B = wT [512][512] bf16 (B[n][k] = W[k][n])
__global__ __launch_bounds__(256) void gemm_k(const __bf16* __restrict__ A,
                                              const __bf16* __restrict__ B,
                                              const float* __restrict__ bias,
                                              const float* __restrict__ norm,
                                              float* __restrict__ C) {
  __shared__ __bf16 As[128 * 64];
  __shared__ __bf16 Bs[128 * 64];
  const int tid = threadIdx.x;
  const int lane = tid & 63;
  const int wv = tid >> 6;          // 4 waves
  const int wr = wv >> 1, wc = wv & 1;
  const int m0 = blockIdx.x * 128;
  const int n0 = blockIdx.y * 128;

  f32x4 acc[4][4] = {};

  const int lr = lane >> 3;          // 0..7: row within 8-row group
  const int lk = (lane & 7) * 8;     // 0..56: k element offset

  for (int kt = 0; kt < DIM; kt += 64) {
#pragma unroll
    for (int jj = 0; jj < 4; ++jj) {
      const int lrow = wv * 32 + jj * 8;                 // wave-uniform
      int grow = m0 + lrow + lr;
      grow = grow < M_NODES ? grow : (M_NODES - 1);      // clamp tail rows
      async16(&As[lrow * 64], A + (size_t)grow * DIM + kt + lk);
      const int brow = n0 + lrow + lr;                   // N=512 always in range
      async16(&Bs[lrow * 64], B + (size_t)brow * DIM + kt + lk);
    }
    __syncthreads();   // drains vmcnt(0) then barrier
#pragma unroll
    for (int kk = 0; kk < 64; kk += 32) {
      bf16x8 af[4], bfr[4];
#pragma unroll
      for (int m = 0; m < 4; ++m)
        af[m] = *(const bf16x8*)&As[(wr * 64 + m * 16 + (lane & 15)) * 64 + kk + (lane >> 4) * 8];
#pragma unroll
      for (int n = 0; n < 4; ++n)
        bfr[n] = *(const bf16x8*)&Bs[(wc * 64 + n * 16 + (lane & 15)) * 64 + kk + (lane >> 4) * 8];
#pragma unroll
      for (int m = 0; m < 4; ++m)
#pragma unroll
        for (int n = 0; n < 4; ++n)
          acc[m][n] = __builtin_amdgcn_mfma_f32_16x16x32_bf16(af[m], bfr[n], acc[m][n], 0, 0, 0);
    }
    __syncthreads();
  }

  // epilogue: C row = (lane>>4)*4 + reg, col = lane&15 within each 16x16 fragment
#pragma unroll
  for (int m = 0; m < 4; ++m) {
    int rbase = m0 + wr * 64 + m * 16 + (lane >> 4) * 4;
#pragma unroll
    for (int r = 0; r < 4; ++r) {
      int row = rbase + r;
      if (row < M_NODES) {
        float nv = norm[row];
#pragma unroll
        for (int n = 0; n < 4; ++n) {
          int col = n0 + wc * 64 + n * 16 + (lane & 15);
          float v = acc[m][n][r] * nv + bias[col];
          C[(size_t)row * DIM + col] = v > 0.f ? v : 0.f;
        }
      }
    }
  }
}

// ---------------- workspace layout ----------------
#define HB_OFF   0UL                     // 20,480,000 B  bf16 h*norm
#define AGG_OFF  20480000UL              // 20,480,000 B  bf16 aggregate
#define WT_OFF   40960000UL              //    524,288 B  bf16 W^T
#define CNT_OFF  41484288UL              //     80,000 B  counts -> cursor
#define OFS_OFF  41564288UL              //     80,256 B  offsets[20001]
#define ESRC_OFF 41644544UL              //  1,280,000 B  CSR src indices
#define WS_NEEDED 42924544UL

extern "C" void kernel_launch(void* const* d_in, const int* in_sizes, int n_in,
                              void* d_out, int out_size, void* d_ws, size_t ws_size,
                              hipStream_t stream) {
  const float* h    = (const float*)d_in[0];
  const float* w    = (const float*)d_in[1];
  const float* bias = (const float*)d_in[2];
  const float* norm = (const float*)d_in[3];
  const int*   src  = (const int*)d_in[4];
  const int*   dst  = (const int*)d_in[5];
  float* out = (float*)d_out;

  if (ws_size < WS_NEEDED) return;  // clean failure signal instead of OOB

  char* ws = (char*)d_ws;
  __bf16* hb      = (__bf16*)(ws + HB_OFF);
  __bf16* aggb    = (__bf16*)(ws + AGG_OFF);
  __bf16* wT      = (__bf16*)(ws + WT_OFF);
  int*    counts  = (int*)(ws + CNT_OFF);
  int*    offsets = (int*)(ws + OFS_OFF);
  int*    esrc    = (int*)(ws + ESRC_OFF);

  hipMemsetAsync(counts, 0, M_NODES * sizeof(int), stream);
  convert_k<<<10000, 256, 0, stream>>>(h, norm, hb);
  transpose_w<<<dim3(16, 16), dim3(32, 32), 0, stream>>>(w, wT);
  count_k<<<1250, 256, 0, stream>>>(dst, counts);
  scan_k<<<1, 1024, 0, stream>>>(counts, offsets);
  fill_k<<<1250, 256, 0, stream>>>(src, dst, counts, esrc);
  aggregate_k<<<40000, 256, 0, stream>>>(hb, offsets, esrc, aggb);
  gemm_k<<<dim3(157, 4), 256, 0, stream>>>(aggb, wT, bias, norm, out);
}

// Round 3
// 148.965 us; speedup vs baseline: 1.0993x; 1.0993x over previous
//
#include <hip/hip_runtime.h>

#define M_NODES 20000
#define N_EDGES_C 320000
#define DIM 512

typedef __attribute__((ext_vector_type(4))) float f32x4;
typedef __attribute__((ext_vector_type(2))) __bf16 bf16x2;
typedef __attribute__((ext_vector_type(4))) __bf16 bf16x4;
typedef __attribute__((ext_vector_type(8))) __bf16 bf16x8;

// ---------------- async global->LDS (16B per lane) ----------------
__device__ __forceinline__ void async16(__bf16* lds, const __bf16* g) {
  __builtin_amdgcn_global_load_lds(
      (const __attribute__((address_space(1))) void*)g,
      (__attribute__((address_space(3))) void*)lds, 16, 0, 0);
}

// ---------------- 1. convert: hb = bf16(norm[row] * h) ----------------
__global__ __launch_bounds__(256) void convert_k(const float* __restrict__ h,
                                                 const float* __restrict__ norm,
                                                 __bf16* __restrict__ hb) {
  int i = blockIdx.x * 256 + threadIdx.x;   // one float4 group each; 2,560,000 total
  int elem = i * 4;
  int row = elem >> 9;
  float s = norm[row];
  f32x4 v = *(const f32x4*)&h[elem];
  bf16x4 o;
  o.x = (__bf16)(v.x * s);
  o.y = (__bf16)(v.y * s);
  o.z = (__bf16)(v.z * s);
  o.w = (__bf16)(v.w * s);
  *(bf16x4*)&hb[elem] = o;
}

// ---------------- 2. weight transpose -> bf16 W^T [n][k] ----------------
__global__ void transpose_w(const float* __restrict__ w, __bf16* __restrict__ wT) {
  __shared__ float tile[32][33];
  int bx = blockIdx.x * 32, by = blockIdx.y * 32;
  int tx = threadIdx.x, ty = threadIdx.y;
  tile[ty][tx] = w[(by + ty) * DIM + bx + tx];   // coalesced read of weight[k][n]
  __syncthreads();
  wT[(bx + ty) * DIM + by + tx] = (__bf16)tile[tx][ty];  // coalesced write of wT[n][k]
}

// ---------------- 3. CSR build ----------------
__global__ __launch_bounds__(256) void count_k(const int* __restrict__ dst,
                                               int* __restrict__ counts) {
  int e = blockIdx.x * 256 + threadIdx.x;
  if (e < N_EDGES_C) atomicAdd(&counts[dst[e]], 1);
}

// single-block scan: 1000 threads x 20 consecutive elements, ~3 global round-trips
__global__ __launch_bounds__(1024) void scan_k(int* __restrict__ counts,
                                               int* __restrict__ offsets) {
  const int tid = threadIdx.x;
  const int lane = tid & 63, wid = tid >> 6;
  __shared__ int wsum[16], wpre[16];
  int v[20];
  int s = 0;
  const int base = tid * 20;
  if (tid < 1000) {
#pragma unroll
    for (int i = 0; i < 20; ++i) { v[i] = counts[base + i]; s += v[i]; }
  }
  int x = s;
#pragma unroll
  for (int off = 1; off < 64; off <<= 1) {
    int t = __shfl_up(x, off, 64);
    if (lane >= off) x += t;
  }
  if (lane == 63) wsum[wid] = x;
  __syncthreads();
  if (wid == 0 && lane < 16) {
    int wv = wsum[lane];
#pragma unroll
    for (int off = 1; off < 16; off <<= 1) {
      int t = __shfl_up(wv, off, 64);
      if (lane >= off) wv += t;
    }
    wpre[lane] = wv;
  }
  __syncthreads();
  const int wbase = wid ? wpre[wid - 1] : 0;
  const int excl = wbase + x - s;    // exclusive prefix over thread sums
  if (tid < 1000) {
    int run = excl;
#pragma unroll
    for (int i = 0; i < 20; ++i) {
      offsets[base + i] = run;
      counts[base + i] = run;        // counts reused as fill cursor
      run += v[i];
    }
  }
  if (tid == 0) offsets[M_NODES] = wpre[15];
}

__global__ __launch_bounds__(256) void fill_k(const int* __restrict__ src,
                                              const int* __restrict__ dst,
                                              int* __restrict__ cursor,
                                              int* __restrict__ esrc) {
  int e = blockIdx.x * 256 + threadIdx.x;
  if (e < N_EDGES_C) {
    int p = atomicAdd(&cursor[dst[e]], 1);
    esrc[p] = src[e];
  }
}

// ---------------- 4. aggregate, XCD-pinned D-panels, full-width loads ----------------
// panel = blockIdx.x % 8 -> round-robin dispatch pins panel p to XCD p
// (panel working set 20000 x 64 x 2B = 2.56 MB < 4 MB per-XCD L2; R2 measured
// FETCH_SIZE 134->15 MB, so the pinning holds).
// Wave layout: 8 edge-slots x 8 col-groups. Each 8-lane group loads one edge's
// full 64-col panel row as bf16x8 (16 B/lane -> 1024 B per wave instruction).
// 8 edges in flight per wave; 3 shfl_xor rounds fold the slots.
__global__ __launch_bounds__(256) void aggregate_k(const __bf16* __restrict__ hb,
                                                   const int* __restrict__ offs,
                                                   const int* __restrict__ esrc,
                                                   __bf16* __restrict__ aggb) {
  const int panel = blockIdx.x & 7;           // -> XCD id (round-robin dispatch)
  const int group = blockIdx.x >> 3;
  const int wv = threadIdx.x >> 6;
  const int node = group * 4 + wv;
  const int lane = threadIdx.x & 63;
  const int slot = lane >> 3;                 // 0..7: edge slot
  const int cg = lane & 7;                    // 0..7: column group (8 cols each)

  const int beg = offs[node], end = offs[node + 1];
  const size_t pbase = (size_t)panel * 64 + cg * 8;

  float a[8] = {};
  for (int j0 = beg; j0 < end; j0 += 8) {
    const int j = j0 + slot;
    if (j < end) {
      const int s = esrc[j];
      bf16x8 v = *(const bf16x8*)&hb[(size_t)s * DIM + pbase];
#pragma unroll
      for (int q = 0; q < 8; ++q) a[q] += (float)v[q];
    }
  }
  // fold the 8 edge slots (lanes differing in bits 3..5 share a col group)
#pragma unroll
  for (int m = 8; m < 64; m <<= 1) {
#pragma unroll
    for (int q = 0; q < 8; ++q) a[q] += __shfl_xor(a[q], m, 64);
  }
  if (slot == 0) {
    bf16x8 o;
#pragma unroll
    for (int q = 0; q < 8; ++q) o[q] = (__bf16)a[q];
    *(bf16x8*)&aggb[(size_t)node * DIM + pbase] = o;
  }
}

// ---------------- 5. GEMM: out = relu(norm * (aggb @ W) + bias) ----------------
// A = aggb [M][512] bf16 row-major; B = wT [512][512] bf16 (B[n][k] = W[k][n])
__global__ __launch_bounds__(256) void gemm_k(const __bf16* __restrict__ A,
                                              const __bf16* __restrict__ B,
                                              const float* __restrict__ bias,
                                              const float* __restrict__ norm,
                                              float* __restrict__ C) {
  __shared__ __bf16 As[128 * 64];
  __shared__ __bf16 Bs[128 * 64];
  const int tid = threadIdx.x;
  const int lane = tid & 63;
  const int wv = tid >> 6;          // 4 waves
  const int wr = wv >> 1, wc = wv & 1;
  const int m0 = blockIdx.x * 128;
  const int n0 = blockIdx.y * 128;

  f32x4 acc[4][4] = {};

  const int lr = lane >> 3;          // 0..7: row within 8-row group
  const int lk = (lane & 7) * 8;     // 0..56: k element offset

  for (int kt = 0; kt < DIM; kt += 64) {
#pragma unroll
    for (int jj = 0; jj < 4; ++jj) {
      const int lrow = wv * 32 + jj * 8;                 // wave-uniform
      int grow = m0 + lrow + lr;
      grow = grow < M_NODES ? grow : (M_NODES - 1);      // clamp tail rows
      async16(&As[lrow * 64], A + (size_t)grow * DIM + kt + lk);
      const int brow = n0 + lrow + lr;                   // N=512 always in range
      async16(&Bs[lrow * 64], B + (size_t)brow * DIM + kt + lk);
    }
    __syncthreads();   // drains vmcnt(0) then barrier
#pragma unroll
    for (int kk = 0; kk < 64; kk += 32) {
      bf16x8 af[4], bfr[4];
#pragma unroll
      for (int m = 0; m < 4; ++m)
        af[m] = *(const bf16x8*)&As[(wr * 64 + m * 16 + (lane & 15)) * 64 + kk + (lane >> 4) * 8];
#pragma unroll
      for (int n = 0; n < 4; ++n)
        bfr[n] = *(const bf16x8*)&Bs[(wc * 64 + n * 16 + (lane & 15)) * 64 + kk + (lane >> 4) * 8];
#pragma unroll
      for (int m = 0; m < 4; ++m)
#pragma unroll
        for (int n = 0; n < 4; ++n)
          acc[m][n] = __builtin_amdgcn_mfma_f32_16x16x32_bf16(af[m], bfr[n], acc[m][n], 0, 0, 0);
    }
    __syncthreads();
  }

  // epilogue: C row = (lane>>4)*4 + reg, col = lane&15 within each 16x16 fragment
#pragma unroll
  for (int m = 0; m < 4; ++m) {
    int rbase = m0 + wr * 64 + m * 16 + (lane >> 4) * 4;
#pragma unroll
    for (int r = 0; r < 4; ++r) {
      int row = rbase + r;
      if (row < M_NODES) {
        float nv = norm[row];
#pragma unroll
        for (int n = 0; n < 4; ++n) {
          int col = n0 + wc * 64 + n * 16 + (lane & 15);
          float v = acc[m][n][r] * nv + bias[col];
          C[(size_t)row * DIM + col] = v > 0.f ? v : 0.f;
        }
      }
    }
  }
}

// ---------------- workspace layout ----------------
#define HB_OFF   0UL                     // 20,480,000 B  bf16 h*norm
#define AGG_OFF  20480000UL              // 20,480,000 B  bf16 aggregate
#define WT_OFF   40960000UL              //    524,288 B  bf16 W^T
#define CNT_OFF  41484288UL              //     80,000 B  counts -> cursor
#define OFS_OFF  41564288UL              //     80,256 B  offsets[20001]
#define ESRC_OFF 41644544UL              //  1,280,000 B  CSR src indices
#define WS_NEEDED 42924544UL

extern "C" void kernel_launch(void* const* d_in, const int* in_sizes, int n_in,
                              void* d_out, int out_size, void* d_ws, size_t ws_size,
                              hipStream_t stream) {
  const float* h    = (const float*)d_in[0];
  const float* w    = (const float*)d_in[1];
  const float* bias = (const float*)d_in[2];
  const float* norm = (const float*)d_in[3];
  const int*   src  = (const int*)d_in[4];
  const int*   dst  = (const int*)d_in[5];
  float* out = (float*)d_out;

  if (ws_size < WS_NEEDED) return;  // clean failure signal instead of OOB

  char* ws = (char*)d_ws;
  __bf16* hb      = (__bf16*)(ws + HB_OFF);
  __bf16* aggb    = (__bf16*)(ws + AGG_OFF);
  __bf16* wT      = (__bf16*)(ws + WT_OFF);
  int*    counts  = (int*)(ws + CNT_OFF);
  int*    offsets = (int*)(ws + OFS_OFF);
  int*    esrc    = (int*)(ws + ESRC_OFF);

  hipMemsetAsync(counts, 0, M_NODES * sizeof(int), stream);
  convert_k<<<10000, 256, 0, stream>>>(h, norm, hb);
  transpose_w<<<dim3(16, 16), dim3(32, 32), 0, stream>>>(w, wT);
  count_k<<<1250, 256, 0, stream>>>(dst, counts);
  scan_k<<<1, 1024, 0, stream>>>(counts, offsets);
  fill_k<<<1250, 256, 0, stream>>>(src, dst, counts, esrc);
  aggregate_k<<<40000, 256, 0, stream>>>(hb, offsets, esrc, aggb);
  gemm_k<<<dim3(157, 4), 256, 0, stream>>>(aggb, wT, bias, norm, out);
}

// Round 4
// 125.647 us; speedup vs baseline: 1.3033x; 1.1856x over previous
//
#include <hip/hip_runtime.h>

#define M_NODES 20000
#define N_EDGES_C 320000
#define DIM 512

typedef __attribute__((ext_vector_type(4))) float f32x4;
typedef __attribute__((ext_vector_type(4))) __bf16 bf16x4;
typedef __attribute__((ext_vector_type(8))) __bf16 bf16x8;

// ---------------- async global->LDS (16B per lane) ----------------
__device__ __forceinline__ void async16(__bf16* lds, const __bf16* g) {
  __builtin_amdgcn_global_load_lds(
      (const __attribute__((address_space(1))) void*)g,
      (__attribute__((address_space(3))) void*)lds, 16, 0, 0);
}

// ---------------- 1. convert: hb = bf16(norm[row] * h) ----------------
__global__ __launch_bounds__(256) void convert_k(const float* __restrict__ h,
                                                 const float* __restrict__ norm,
                                                 __bf16* __restrict__ hb) {
  int i = blockIdx.x * 256 + threadIdx.x;   // one float4 group each; 2,560,000 total
  int elem = i * 4;
  int row = elem >> 9;
  float s = norm[row];
  f32x4 v = *(const f32x4*)&h[elem];
  bf16x4 o;
  o.x = (__bf16)(v.x * s);
  o.y = (__bf16)(v.y * s);
  o.z = (__bf16)(v.z * s);
  o.w = (__bf16)(v.w * s);
  *(bf16x4*)&hb[elem] = o;
}

// ---------------- 2. weight transpose -> bf16 W^T [n][k] ----------------
__global__ void transpose_w(const float* __restrict__ w, __bf16* __restrict__ wT) {
  __shared__ float tile[32][33];
  int bx = blockIdx.x * 32, by = blockIdx.y * 32;
  int tx = threadIdx.x, ty = threadIdx.y;
  tile[ty][tx] = w[(by + ty) * DIM + bx + tx];   // coalesced read of weight[k][n]
  __syncthreads();
  wT[(bx + ty) * DIM + by + tx] = (__bf16)tile[tx][ty];  // coalesced write of wT[n][k]
}

// ---------------- 3. CSR build ----------------
__global__ __launch_bounds__(256) void count_k(const int* __restrict__ dst,
                                               int* __restrict__ counts) {
  int e = blockIdx.x * 256 + threadIdx.x;
  if (e < N_EDGES_C) atomicAdd(&counts[dst[e]], 1);
}

// single-block scan: 1000 threads x 20 consecutive elements, ~3 global round-trips
__global__ __launch_bounds__(1024) void scan_k(int* __restrict__ counts,
                                               int* __restrict__ offsets) {
  const int tid = threadIdx.x;
  const int lane = tid & 63, wid = tid >> 6;
  __shared__ int wsum[16], wpre[16];
  int v[20];
  int s = 0;
  const int base = tid * 20;
  if (tid < 1000) {
#pragma unroll
    for (int i = 0; i < 20; ++i) { v[i] = counts[base + i]; s += v[i]; }
  }
  int x = s;
#pragma unroll
  for (int off = 1; off < 64; off <<= 1) {
    int t = __shfl_up(x, off, 64);
    if (lane >= off) x += t;
  }
  if (lane == 63) wsum[wid] = x;
  __syncthreads();
  if (wid == 0 && lane < 16) {
    int wv = wsum[lane];
#pragma unroll
    for (int off = 1; off < 16; off <<= 1) {
      int t = __shfl_up(wv, off, 64);
      if (lane >= off) wv += t;
    }
    wpre[lane] = wv;
  }
  __syncthreads();
  const int wbase = wid ? wpre[wid - 1] : 0;
  const int excl = wbase + x - s;    // exclusive prefix over thread sums
  if (tid < 1000) {
    int run = excl;
#pragma unroll
    for (int i = 0; i < 20; ++i) {
      offsets[base + i] = run;
      counts[base + i] = run;        // counts reused as fill cursor
      run += v[i];
    }
  }
  if (tid == 0) offsets[M_NODES] = wpre[15];
}

__global__ __launch_bounds__(256) void fill_k(const int* __restrict__ src,
                                              const int* __restrict__ dst,
                                              int* __restrict__ cursor,
                                              int* __restrict__ esrc) {
  int e = blockIdx.x * 256 + threadIdx.x;
  if (e < N_EDGES_C) {
    int p = atomicAdd(&cursor[dst[e]], 1);
    esrc[p] = src[e];
  }
}

// ---------------- 4. aggregate: XCD-pinned panels, 8 nodes/wave, no fold ----------------
// panel = blockIdx.x % 8 -> round-robin dispatch pins panel p to XCD p
// (2.56 MB panel working set < 4 MB per-XCD L2; R2/R3 measured FETCH 134->15 MB).
// Wave = 8 node-groups x 8 lanes. Group g owns node_base+g and walks its whole
// edge list; each lane accumulates its own 8-col slice in registers -> no
// cross-lane fold, offs/esrc latency amortized over the full edge walk.
__global__ __launch_bounds__(256) void aggregate_k(const __bf16* __restrict__ hb,
                                                   const int* __restrict__ offs,
                                                   const int* __restrict__ esrc,
                                                   __bf16* __restrict__ aggb) {
  const int panel = blockIdx.x & 7;           // -> XCD id (round-robin dispatch)
  const int nb = blockIdx.x >> 3;             // 0..624
  const int wv = threadIdx.x >> 6;
  const int lane = threadIdx.x & 63;
  const int slot = lane >> 3;                 // 0..7: node sub-index within wave
  const int cg = lane & 7;                    // 0..7: column group (8 cols)
  const int node = nb * 32 + wv * 8 + slot;   // 625*32 = 20000 exactly

  const int beg = offs[node], end = offs[node + 1];
  const size_t pbase = (size_t)panel * 64 + cg * 8;

  float a[8] = {};
  int j = beg;
  for (; j + 1 < end; j += 2) {               // 2 gathers in flight
    const int s0 = esrc[j];
    const int s1 = esrc[j + 1];
    bf16x8 v0 = *(const bf16x8*)&hb[(size_t)s0 * DIM + pbase];
    bf16x8 v1 = *(const bf16x8*)&hb[(size_t)s1 * DIM + pbase];
#pragma unroll
    for (int q = 0; q < 8; ++q) a[q] += (float)v0[q] + (float)v1[q];
  }
  if (j < end) {
    const int s0 = esrc[j];
    bf16x8 v0 = *(const bf16x8*)&hb[(size_t)s0 * DIM + pbase];
#pragma unroll
    for (int q = 0; q < 8; ++q) a[q] += (float)v0[q];
  }
  bf16x8 o;
#pragma unroll
  for (int q = 0; q < 8; ++q) o[q] = (__bf16)a[q];
  *(bf16x8*)&aggb[(size_t)node * DIM + pbase] = o;
}

// ---------------- 5. GEMM: out = relu(norm * (aggb @ W) + bias) ----------------
// A = aggb [M][512] bf16 row-major; B = wT [512][512] bf16 (B[n][k] = W[k][n])
__global__ __launch_bounds__(256) void gemm_k(const __bf16* __restrict__ A,
                                              const __bf16* __restrict__ B,
                                              const float* __restrict__ bias,
                                              const float* __restrict__ norm,
                                              float* __restrict__ C) {
  __shared__ __bf16 As[128 * 64];
  __shared__ __bf16 Bs[128 * 64];
  const int tid = threadIdx.x;
  const int lane = tid & 63;
  const int wv = tid >> 6;          // 4 waves
  const int wr = wv >> 1, wc = wv & 1;
  const int m0 = blockIdx.x * 128;
  const int n0 = blockIdx.y * 128;

  f32x4 acc[4][4] = {};

  const int lr = lane >> 3;          // 0..7: row within 8-row group
  const int lk = (lane & 7) * 8;     // 0..56: k element offset

  for (int kt = 0; kt < DIM; kt += 64) {
#pragma unroll
    for (int jj = 0; jj < 4; ++jj) {
      const int lrow = wv * 32 + jj * 8;                 // wave-uniform
      int grow = m0 + lrow + lr;
      grow = grow < M_NODES ? grow : (M_NODES - 1);      // clamp tail rows
      async16(&As[lrow * 64], A + (size_t)grow * DIM + kt + lk);
      const int brow = n0 + lrow + lr;                   // N=512 always in range
      async16(&Bs[lrow * 64], B + (size_t)brow * DIM + kt + lk);
    }
    __syncthreads();   // drains vmcnt(0) then barrier
#pragma unroll
    for (int kk = 0; kk < 64; kk += 32) {
      bf16x8 af[4], bfr[4];
#pragma unroll
      for (int m = 0; m < 4; ++m)
        af[m] = *(const bf16x8*)&As[(wr * 64 + m * 16 + (lane & 15)) * 64 + kk + (lane >> 4) * 8];
#pragma unroll
      for (int n = 0; n < 4; ++n)
        bfr[n] = *(const bf16x8*)&Bs[(wc * 64 + n * 16 + (lane & 15)) * 64 + kk + (lane >> 4) * 8];
#pragma unroll
      for (int m = 0; m < 4; ++m)
#pragma unroll
        for (int n = 0; n < 4; ++n)
          acc[m][n] = __builtin_amdgcn_mfma_f32_16x16x32_bf16(af[m], bfr[n], acc[m][n], 0, 0, 0);
    }
    __syncthreads();
  }

  // epilogue: C row = (lane>>4)*4 + reg, col = lane&15 within each 16x16 fragment
#pragma unroll
  for (int m = 0; m < 4; ++m) {
    int rbase = m0 + wr * 64 + m * 16 + (lane >> 4) * 4;
#pragma unroll
    for (int r = 0; r < 4; ++r) {
      int row = rbase + r;
      if (row < M_NODES) {
        float nv = norm[row];
#pragma unroll
        for (int n = 0; n < 4; ++n) {
          int col = n0 + wc * 64 + n * 16 + (lane & 15);
          float v = acc[m][n][r] * nv + bias[col];
          C[(size_t)row * DIM + col] = v > 0.f ? v : 0.f;
        }
      }
    }
  }
}

// ---------------- workspace layout ----------------
#define HB_OFF   0UL                     // 20,480,000 B  bf16 h*norm
#define AGG_OFF  20480000UL              // 20,480,000 B  bf16 aggregate
#define WT_OFF   40960000UL              //    524,288 B  bf16 W^T
#define CNT_OFF  41484288UL              //     80,000 B  counts -> cursor
#define OFS_OFF  41564288UL              //     80,256 B  offsets[20001]
#define ESRC_OFF 41644544UL              //  1,280,000 B  CSR src indices
#define WS_NEEDED 42924544UL

extern "C" void kernel_launch(void* const* d_in, const int* in_sizes, int n_in,
                              void* d_out, int out_size, void* d_ws, size_t ws_size,
                              hipStream_t stream) {
  const float* h    = (const float*)d_in[0];
  const float* w    = (const float*)d_in[1];
  const float* bias = (const float*)d_in[2];
  const float* norm = (const float*)d_in[3];
  const int*   src  = (const int*)d_in[4];
  const int*   dst  = (const int*)d_in[5];
  float* out = (float*)d_out;

  if (ws_size < WS_NEEDED) return;  // clean failure signal instead of OOB

  char* ws = (char*)d_ws;
  __bf16* hb      = (__bf16*)(ws + HB_OFF);
  __bf16* aggb    = (__bf16*)(ws + AGG_OFF);
  __bf16* wT      = (__bf16*)(ws + WT_OFF);
  int*    counts  = (int*)(ws + CNT_OFF);
  int*    offsets = (int*)(ws + OFS_OFF);
  int*    esrc    = (int*)(ws + ESRC_OFF);

  hipMemsetAsync(counts, 0, M_NODES * sizeof(int), stream);
  convert_k<<<10000, 256, 0, stream>>>(h, norm, hb);
  transpose_w<<<dim3(16, 16), dim3(32, 32), 0, stream>>>(w, wT);
  count_k<<<1250, 256, 0, stream>>>(dst, counts);
  scan_k<<<1, 1024, 0, stream>>>(counts, offsets);
  fill_k<<<1250, 256, 0, stream>>>(src, dst, counts, esrc);
  aggregate_k<<<5000, 256, 0, stream>>>(hb, offsets, esrc, aggb);
  gemm_k<<<dim3(157, 4), 256, 0, stream>>>(aggb, wT, bias, norm, out);
}